// Round 8
// baseline (214.786 us; speedup 1.0000x reference)
//
#include <hip/hip_runtime.h>
#include <cfloat>

#define M_UP   32768
#define N_DOWN 8192
#define UPC    128
#define DOWNC  256
#define OUTC   128
#define G      8                   // selection group size
#define Q      2                   // queries per thread (amortizes LDS reads)
#define PG     12                  // padded group stride in floats (48B)

__device__ __forceinline__ void fma4(float4& acc, float s, const float4 w) {
    acc.x = fmaf(s, w.x, acc.x);
    acc.y = fmaf(s, w.y, acc.y);
    acc.z = fmaf(s, w.z, acc.z);
    acc.w = fmaf(s, w.w, acc.w);
}

// Branchless stable top-3 insert with index tracking.
// Strict < everywhere => earlier-inserted wins ties (stable in scan order),
// matching jax.lax.top_k's lower-index-first tie-break.
__device__ __forceinline__ void top3_bl(float s, int idx,
                                        float& d0, float& d1, float& d2,
                                        int& i0, int& i1, int& i2) {
    bool c0 = s < d0, c1 = s < d1, c2 = s < d2;
    float n0 = fminf(d0, s);
    float n1 = __builtin_amdgcn_fmed3f(d0, d1, s);
    float n2 = __builtin_amdgcn_fmed3f(d1, d2, s);
    int m0 = c0 ? idx : i0;
    int m1 = c0 ? i0 : (c1 ? idx : i1);
    int m2 = c1 ? i1 : (c2 ? idx : i2);
    d0 = n0; d1 = n1; d2 = n2;
    i0 = m0; i1 = m1; i2 = m2;
}

// ---------------------------------------------------------------------------
// K0: transpose weights for coalesced float4 GEMM reads.
// ---------------------------------------------------------------------------
__global__ __launch_bounds__(256) void transpose_w(
        const float* __restrict__ W_up, const float* __restrict__ W_down,
        float* __restrict__ wt_up, float* __restrict__ wt_down) {
    int e = blockIdx.x * 256 + threadIdx.x;
    if (e < DOWNC * OUTC) {
        int k = e >> 7, c = e & 127;
        wt_down[e] = W_down[c * DOWNC + k];
    } else {
        int e2 = e - DOWNC * OUTC;
        int k = e2 >> 7, c = e2 & 127;
        wt_up[e2] = W_up[c * UPC + k];
    }
}

// ---------------------------------------------------------------------------
// K1: down_f = down_features @ W_down.T + b_down  (8192 x 128)
// Unchanged from R7 (all-LDS operands) for clean attribution; counters
// expected to become visible in R8's top-5.
// ---------------------------------------------------------------------------
__global__ __launch_bounds__(256) void down_proj(
        const float* __restrict__ A, const float* __restrict__ WT,
        const float* __restrict__ bias, float* __restrict__ down_f) {
    __shared__ __align__(16) float sA[16 * DOWNC];          // 16 KB
    __shared__ __align__(16) float sW[64 * OUTC];           // 32 KB
    {
        const float4* Ab4 = (const float4*)(A + blockIdx.x * 16 * DOWNC);
        float4* sA4 = (float4*)sA;
        #pragma unroll
        for (int i = 0; i < 4; ++i)
            sA4[threadIdx.x + i * 256] = Ab4[threadIdx.x + i * 256];
    }
    const int c4 = threadIdx.x & 31;
    const int rr = threadIdx.x >> 5;
    float4 acc0 = {0.f, 0.f, 0.f, 0.f};
    float4 acc1 = {0.f, 0.f, 0.f, 0.f};
    for (int kh = 0; kh < 4; ++kh) {                        // 64 k per phase
        if (kh) __syncthreads();
        {
            const float4* W4 = (const float4*)(WT + kh * 64 * OUTC);
            float4* sW4 = (float4*)sW;
            #pragma unroll
            for (int i = 0; i < 8; ++i)
                sW4[threadIdx.x + i * 256] = W4[threadIdx.x + i * 256];
        }
        __syncthreads();
        #pragma unroll 2
        for (int k2 = 0; k2 < 64; k2 += 4) {
            const int k = kh * 64 + k2;
            float4 a0 = *(const float4*)&sA[rr * DOWNC + k];
            float4 a1 = *(const float4*)&sA[(rr + 8) * DOWNC + k];
            const float4* wp = (const float4*)(sW + k2 * OUTC) + c4;
            float4 w0 = wp[0], w1 = wp[32], w2 = wp[64], w3 = wp[96];
            fma4(acc0, a0.x, w0); fma4(acc0, a0.y, w1);
            fma4(acc0, a0.z, w2); fma4(acc0, a0.w, w3);
            fma4(acc1, a1.x, w0); fma4(acc1, a1.y, w1);
            fma4(acc1, a1.z, w2); fma4(acc1, a1.w, w3);
        }
    }
    const int r0 = blockIdx.x * 16 + rr;
    const int r1 = r0 + 8;
    float4 b = ((const float4*)bias)[c4];
    acc0.x += b.x; acc0.y += b.y; acc0.z += b.z; acc0.w += b.w;
    acc1.x += b.x; acc1.y += b.y; acc1.z += b.z; acc1.w += b.w;
    ((float4*)down_f)[r0 * 32 + c4] = acc0;
    ((float4*)down_f)[r1 * 32 + c4] = acc1;
}

// ---------------------------------------------------------------------------
// K2: partial 3-NN, templated on chunk count NC.
// R7 showed OccupancyPercent 19.5% (2 waves/SIMD): parallelism-starved, not
// VALU/LDS-saturated. NC=16 (CHUNK=512) doubles waves to 4/SIMD at constant
// total scan-read count. NC=8 kept as fallback if workspace is tight.
// ---------------------------------------------------------------------------
template <int NC>
__global__ __launch_bounds__(256) void knn_partial(
        const float* __restrict__ up_points,
        const float* __restrict__ down_points,
        float2* __restrict__ part) {            // [NC][M_UP][3]
    constexpr int CH = N_DOWN / NC;             // chunk size
    constexpr int NG = CH / G;                  // groups per chunk
    __shared__ __align__(16) float sx[PG * NG];
    __shared__ __align__(16) float sy[PG * NG];
    __shared__ __align__(16) float sz[PG * NG];
    const int base = blockIdx.y * CH;
    for (int t = threadIdx.x; t < CH; t += 256) {
        int g = base + t;
        int gi = t >> 3, j = t & 7;
        sx[PG * gi + j] = down_points[3 * g];
        sy[PG * gi + j] = down_points[3 * g + 1];
        sz[PG * gi + j] = down_points[3 * g + 2];
    }
    __syncthreads();

    const int m0 = blockIdx.x * (256 * Q) + threadIdx.x;
    const int m1 = m0 + 256;
    const float q0x = up_points[3 * m0];
    const float q0y = up_points[3 * m0 + 1];
    const float q0z = up_points[3 * m0 + 2];
    const float q1x = up_points[3 * m1];
    const float q1y = up_points[3 * m1 + 1];
    const float q1z = up_points[3 * m1 + 2];

    float a_gd0 = FLT_MAX, a_gd1 = FLT_MAX, a_gd2 = FLT_MAX;
    int   a_gi0 = 0, a_gi1 = 0, a_gi2 = 0;
    float b_gd0 = FLT_MAX, b_gd1 = FLT_MAX, b_gd2 = FLT_MAX;
    int   b_gi0 = 0, b_gi1 = 0, b_gi2 = 0;

    for (int gi = 0; gi < NG; ++gi) {
        float4 x0 = *(const float4*)&sx[PG * gi], x1 = *(const float4*)&sx[PG * gi + 4];
        float4 y0 = *(const float4*)&sy[PG * gi], y1 = *(const float4*)&sy[PG * gi + 4];
        float4 z0 = *(const float4*)&sz[PG * gi], z1 = *(const float4*)&sz[PG * gi + 4];
        float px[G] = {x0.x, x0.y, x0.z, x0.w, x1.x, x1.y, x1.z, x1.w};
        float py[G] = {y0.x, y0.y, y0.z, y0.w, y1.x, y1.y, y1.z, y1.w};
        float pz[G] = {z0.x, z0.y, z0.z, z0.w, z1.x, z1.y, z1.z, z1.w};
        float s0[G], s1[G];
        #pragma unroll
        for (int j = 0; j < G; ++j) {
            float dx0 = q0x - px[j], dy0 = q0y - py[j], dz0 = q0z - pz[j];
            s0[j] = fmaf(dz0, dz0, fmaf(dy0, dy0, dx0 * dx0));
            float dx1 = q1x - px[j], dy1 = q1y - py[j], dz1 = q1z - pz[j];
            s1[j] = fmaf(dz1, dz1, fmaf(dy1, dy1, dx1 * dx1));
        }
        float gm0 = fminf(fminf(fminf(s0[0], s0[1]), fminf(s0[2], s0[3])),
                          fminf(fminf(s0[4], s0[5]), fminf(s0[6], s0[7])));
        float gm1 = fminf(fminf(fminf(s1[0], s1[1]), fminf(s1[2], s1[3])),
                          fminf(fminf(s1[4], s1[5]), fminf(s1[6], s1[7])));
        top3_bl(gm0, gi, a_gd0, a_gd1, a_gd2, a_gi0, a_gi1, a_gi2);
        top3_bl(gm1, gi, b_gd0, b_gd1, b_gd2, b_gi0, b_gi1, b_gi2);
    }

    // exact refine over the 3 winning groups (24 points per query)
    #pragma unroll
    for (int qq = 0; qq < Q; ++qq) {
        const float qx = qq ? q1x : q0x;
        const float qy = qq ? q1y : q0y;
        const float qz = qq ? q1z : q0z;
        int bases[3];
        if (qq == 0) { bases[0] = a_gi0; bases[1] = a_gi1; bases[2] = a_gi2; }
        else         { bases[0] = b_gi0; bases[1] = b_gi1; bases[2] = b_gi2; }
        float D0 = FLT_MAX, D1 = FLT_MAX, D2 = FLT_MAX;
        int I0 = 0, I1 = 0, I2 = 0;
        #pragma unroll
        for (int t = 0; t < 3; ++t) {
            const int gb = bases[t];
            float4 x0 = *(const float4*)&sx[PG * gb], x1 = *(const float4*)&sx[PG * gb + 4];
            float4 y0 = *(const float4*)&sy[PG * gb], y1 = *(const float4*)&sy[PG * gb + 4];
            float4 z0 = *(const float4*)&sz[PG * gb], z1 = *(const float4*)&sz[PG * gb + 4];
            float px[G] = {x0.x, x0.y, x0.z, x0.w, x1.x, x1.y, x1.z, x1.w};
            float py[G] = {y0.x, y0.y, y0.z, y0.w, y1.x, y1.y, y1.z, y1.w};
            float pz[G] = {z0.x, z0.y, z0.z, z0.w, z1.x, z1.y, z1.z, z1.w};
            #pragma unroll
            for (int j = 0; j < G; ++j) {
                float dx = qx - px[j], dy = qy - py[j], dz = qz - pz[j];
                float s = fmaf(dz, dz, fmaf(dy, dy, dx * dx));
                top3_bl(s, base + gb * G + j, D0, D1, D2, I0, I1, I2);
            }
        }
        const int m = qq ? m1 : m0;
        const int o = (blockIdx.y * M_UP + m) * 3;
        part[o]     = make_float2(D0, __int_as_float(I0));
        part[o + 1] = make_float2(D1, __int_as_float(I1));
        part[o + 2] = make_float2(D2, __int_as_float(I2));
    }
}

// ---------------------------------------------------------------------------
// K3: fused up-projection + top-3 merge + interpolation + bias + add.
// GEMM part unchanged from R7; merge loop templated on NC.
// ---------------------------------------------------------------------------
template <int NC>
__global__ __launch_bounds__(256) void up_fused(
        const float* __restrict__ A, const float* __restrict__ WT,
        const float* __restrict__ bias, const float* __restrict__ down_f,
        const float2* __restrict__ part,
        float* __restrict__ out) {
    __shared__ __align__(16) float sA[16 * UPC];            // 8 KB
    __shared__ __align__(16) float sW[64 * OUTC];           // 32 KB
    {
        const float4* Ab4 = (const float4*)(A + blockIdx.x * 16 * UPC);
        float4* sA4 = (float4*)sA;
        #pragma unroll
        for (int i = 0; i < 2; ++i)
            sA4[threadIdx.x + i * 256] = Ab4[threadIdx.x + i * 256];
    }
    const int c4 = threadIdx.x & 31;
    const int rr = threadIdx.x >> 5;
    const int q0 = blockIdx.x * 16 + rr;
    const int q1 = q0 + 8;
    float4 acc0 = {0.f, 0.f, 0.f, 0.f};
    float4 acc1 = {0.f, 0.f, 0.f, 0.f};
    for (int kh = 0; kh < 2; ++kh) {                        // 64 k per phase
        if (kh) __syncthreads();
        {
            const float4* W4 = (const float4*)(WT + kh * 64 * OUTC);
            float4* sW4 = (float4*)sW;
            #pragma unroll
            for (int i = 0; i < 8; ++i)
                sW4[threadIdx.x + i * 256] = W4[threadIdx.x + i * 256];
        }
        __syncthreads();
        #pragma unroll 2
        for (int k2 = 0; k2 < 64; k2 += 4) {
            const int k = kh * 64 + k2;
            float4 a0 = *(const float4*)&sA[rr * UPC + k];
            float4 a1 = *(const float4*)&sA[(rr + 8) * UPC + k];
            const float4* wp = (const float4*)(sW + k2 * OUTC) + c4;
            float4 w0 = wp[0], w1 = wp[32], w2 = wp[64], w3 = wp[96];
            fma4(acc0, a0.x, w0); fma4(acc0, a0.y, w1);
            fma4(acc0, a0.z, w2); fma4(acc0, a0.w, w3);
            fma4(acc1, a1.x, w0); fma4(acc1, a1.y, w1);
            fma4(acc1, a1.z, w2); fma4(acc1, a1.w, w3);
        }
    }
    const float4 b = ((const float4*)bias)[c4];
    const float4* df4 = (const float4*)down_f;
    #pragma unroll
    for (int t = 0; t < 2; ++t) {
        const int q = t ? q1 : q0;
        float4 acc = t ? acc1 : acc0;
        float D0 = FLT_MAX, D1 = FLT_MAX, D2 = FLT_MAX;
        int I0 = 0, I1 = 0, I2 = 0;
        #pragma unroll
        for (int s = 0; s < NC; ++s) {
            const float2* p = part + (s * M_UP + q) * 3;
            #pragma unroll
            for (int j = 0; j < 3; ++j) {
                float2 v = p[j];
                top3_bl(v.x, __float_as_int(v.y), D0, D1, D2, I0, I1, I2);
            }
        }
        float r0 = 1.f / (D0 + 1e-8f);
        float r1 = 1.f / (D1 + 1e-8f);
        float r2 = 1.f / (D2 + 1e-8f);
        float rs = (r0 + r1) + r2;
        float w0 = r0 / rs, w1 = r1 / rs, w2 = r2 / rs;
        float4 f0 = df4[I0 * 32 + c4];
        float4 f1 = df4[I1 * 32 + c4];
        float4 f2 = df4[I2 * 32 + c4];
        float4 res;
        res.x = acc.x + b.x + fmaf(w0, f0.x, fmaf(w1, f1.x, w2 * f2.x));
        res.y = acc.y + b.y + fmaf(w0, f0.y, fmaf(w1, f1.y, w2 * f2.y));
        res.z = acc.z + b.z + fmaf(w0, f0.z, fmaf(w1, f1.z, w2 * f2.z));
        res.w = acc.w + b.w + fmaf(w0, f0.w, fmaf(w1, f1.w, w2 * f2.w));
        ((float4*)out)[q * 32 + c4] = res;
    }
}

extern "C" void kernel_launch(void* const* d_in, const int* in_sizes, int n_in,
                              void* d_out, int out_size, void* d_ws, size_t ws_size,
                              hipStream_t stream) {
    const float* up_points     = (const float*)d_in[0];
    const float* up_features   = (const float*)d_in[1];
    const float* down_points   = (const float*)d_in[2];
    const float* down_features = (const float*)d_in[3];
    const float* W_up          = (const float*)d_in[4];
    const float* b_up          = (const float*)d_in[5];
    const float* W_down        = (const float*)d_in[6];
    const float* b_down        = (const float*)d_in[7];
    float* out = (float*)d_out;

    float* wt_down = (float*)d_ws;                         // 256*128
    float* wt_up   = wt_down + DOWNC * OUTC;               // 128*128
    float* down_f  = wt_up + UPC * OUTC;                   // 8192*128
    float2* part   = (float2*)(down_f + N_DOWN * OUTC);

    const size_t base_bytes =
        (size_t)(DOWNC * OUTC + UPC * OUTC + N_DOWN * OUTC) * sizeof(float);
    const size_t need16 = base_bytes + (size_t)16 * M_UP * 3 * sizeof(float2);
    const bool big = ws_size >= need16;   // ~17 MB for NC=16, else ~10.7 MB

    transpose_w<<<(DOWNC * OUTC + UPC * OUTC) / 256, 256, 0, stream>>>(
        W_up, W_down, wt_up, wt_down);
    down_proj<<<N_DOWN / 16, 256, 0, stream>>>(
        down_features, wt_down, b_down, down_f);
    if (big) {
        knn_partial<16><<<dim3(M_UP / (256 * Q), 16), 256, 0, stream>>>(
            up_points, down_points, part);
        up_fused<16><<<M_UP / 16, 256, 0, stream>>>(
            up_features, wt_up, b_up, down_f, part, out);
    } else {
        knn_partial<8><<<dim3(M_UP / (256 * Q), 8), 256, 0, stream>>>(
            up_points, down_points, part);
        up_fused<8><<<M_UP / 16, 256, 0, stream>>>(
            up_features, wt_up, b_up, down_f, part, out);
    }
}

// Round 9
// 188.189 us; speedup vs baseline: 1.1413x; 1.1413x over previous
//
#include <hip/hip_runtime.h>
#include <cfloat>

#define M_UP   32768
#define N_DOWN 8192
#define UPC    128
#define DOWNC  256
#define OUTC   128
#define NCHUNK 8
#define CHUNK  (N_DOWN / NCHUNK)   // 1024
#define G      8                   // selection group size
#define Q      2                   // queries per thread (amortizes LDS reads)
#define PG     12                  // padded group stride in floats (48B)

__device__ __forceinline__ void fma4(float4& acc, float s, const float4 w) {
    acc.x = fmaf(s, w.x, acc.x);
    acc.y = fmaf(s, w.y, acc.y);
    acc.z = fmaf(s, w.z, acc.z);
    acc.w = fmaf(s, w.w, acc.w);
}

// Branchless stable top-3 insert with index tracking.
// Strict < everywhere => earlier-inserted wins ties (stable in scan order),
// matching jax.lax.top_k's lower-index-first tie-break.
__device__ __forceinline__ void top3_bl(float s, int idx,
                                        float& d0, float& d1, float& d2,
                                        int& i0, int& i1, int& i2) {
    bool c0 = s < d0, c1 = s < d1, c2 = s < d2;
    float n0 = fminf(d0, s);
    float n1 = __builtin_amdgcn_fmed3f(d0, d1, s);
    float n2 = __builtin_amdgcn_fmed3f(d1, d2, s);
    int m0 = c0 ? idx : i0;
    int m1 = c0 ? i0 : (c1 ? idx : i1);
    int m2 = c1 ? i1 : (c2 ? idx : i2);
    d0 = n0; d1 = n1; d2 = n2;
    i0 = m0; i1 = m1; i2 = m2;
}

// ---------------------------------------------------------------------------
// K0: transpose weights for coalesced float4 GEMM reads.
// ---------------------------------------------------------------------------
__global__ __launch_bounds__(256) void transpose_w(
        const float* __restrict__ W_up, const float* __restrict__ W_down,
        float* __restrict__ wt_up, float* __restrict__ wt_down) {
    int e = blockIdx.x * 256 + threadIdx.x;
    if (e < DOWNC * OUTC) {
        int k = e >> 7, c = e & 127;
        wt_down[e] = W_down[c * DOWNC + k];
    } else {
        int e2 = e - DOWNC * OUTC;
        int k = e2 >> 7, c = e2 & 127;
        wt_up[e2] = W_up[c * UPC + k];
    }
}

// ---------------------------------------------------------------------------
// Register-blocked GEMM tile: 32 rows x 128 cols per block, 256 threads,
// per-thread 2 rows x 8 cols (acc = 4 float4). R8 analysis: the old 2x4
// mapping re-read the whole W panel per wave -> 3.2GB LDS traffic in
// up_fused (~46us at the 69TB/s ceiling). This shape does 2 b32 (A) +
// 2 b128 (W) LDS reads per 32 FMAs -> ~4x less LDS traffic, FMA-balanced.
// sA padded to stride 36: A-frag reads 2-way bank-aliased (free, m136);
// sW reads are 16-lane broadcast groups (conflict-free).
// ---------------------------------------------------------------------------
template <int K>
__device__ __forceinline__ void gemm_tile32(
        const float* __restrict__ A, const float* __restrict__ WT,
        float* sA /*[32*36]*/, float* sW /*[32*128]*/,
        int rbase, int tid, float4 acc[2][2]) {
    const int rl = tid & 15;
    const int c0 = (tid >> 4) * 8;
    #pragma unroll 1
    for (int ph = 0; ph < K / 32; ++ph) {
        if (ph) __syncthreads();                 // prev-phase readers done
        {   // stage A: 32 rows x 32 k (1 float4/thread, 128B segments)
            int r = tid >> 3, k4 = tid & 7;
            float4 v = *(const float4*)(A + (size_t)(rbase + r) * K + ph * 32 + k4 * 4);
            *(float4*)&sA[r * 36 + k4 * 4] = v;
        }
        // stage W: 32 k x 128 cols (4 float4/thread, contiguous)
        #pragma unroll
        for (int i = 0; i < 4; ++i) {
            int idx = tid + i * 256;
            int kk = idx >> 5, cc = idx & 31;
            float4 v = *(const float4*)(WT + (size_t)(ph * 32 + kk) * OUTC + cc * 4);
            *(float4*)&sW[kk * OUTC + cc * 4] = v;
        }
        __syncthreads();
        #pragma unroll 4
        for (int kk = 0; kk < 32; ++kk) {
            float a0 = sA[rl * 36 + kk];
            float a1 = sA[(rl + 16) * 36 + kk];
            float4 w0 = *(const float4*)&sW[kk * OUTC + c0];
            float4 w1 = *(const float4*)&sW[kk * OUTC + c0 + 4];
            fma4(acc[0][0], a0, w0); fma4(acc[0][1], a0, w1);
            fma4(acc[1][0], a1, w0); fma4(acc[1][1], a1, w1);
        }
    }
}

// ---------------------------------------------------------------------------
// K1: down_f = down_features @ W_down.T + b_down  (8192 x 128)
// 256 blocks (full chip), 20.6KB LDS, ~50 VGPR.
// ---------------------------------------------------------------------------
__global__ __launch_bounds__(256) void down_proj(
        const float* __restrict__ A, const float* __restrict__ WT,
        const float* __restrict__ bias, float* __restrict__ down_f) {
    __shared__ __align__(16) float sA[32 * 36];
    __shared__ __align__(16) float sW[32 * OUTC];
    float4 acc[2][2] = {};
    gemm_tile32<DOWNC>(A, WT, sA, sW, blockIdx.x * 32, threadIdx.x, acc);
    const int rl = threadIdx.x & 15;
    const int cg = (threadIdx.x >> 4) * 2;       // col float4 index
    const float4 b0 = ((const float4*)bias)[cg];
    const float4 b1 = ((const float4*)bias)[cg + 1];
    #pragma unroll
    for (int i = 0; i < 2; ++i) {
        const int row = blockIdx.x * 32 + rl + 16 * i;
        float4 v0 = acc[i][0], v1 = acc[i][1];
        v0.x += b0.x; v0.y += b0.y; v0.z += b0.z; v0.w += b0.w;
        v1.x += b1.x; v1.y += b1.y; v1.z += b1.z; v1.w += b1.w;
        ((float4*)down_f)[row * 32 + cg] = v0;
        ((float4*)down_f)[row * 32 + cg + 1] = v1;
    }
}

// ---------------------------------------------------------------------------
// K2: partial 3-NN — exact R7 version (proven 65us). NC=8 fixed.
// ---------------------------------------------------------------------------
__global__ __launch_bounds__(256) void knn_partial(
        const float* __restrict__ up_points,
        const float* __restrict__ down_points,
        float2* __restrict__ part) {            // [NCHUNK][M_UP][3]
    __shared__ __align__(16) float sx[PG * (CHUNK / G)];
    __shared__ __align__(16) float sy[PG * (CHUNK / G)];
    __shared__ __align__(16) float sz[PG * (CHUNK / G)];
    const int base = blockIdx.y * CHUNK;
    for (int t = threadIdx.x; t < CHUNK; t += 256) {
        int g = base + t;
        int gi = t >> 3, j = t & 7;
        sx[PG * gi + j] = down_points[3 * g];
        sy[PG * gi + j] = down_points[3 * g + 1];
        sz[PG * gi + j] = down_points[3 * g + 2];
    }
    __syncthreads();

    const int m0 = blockIdx.x * (256 * Q) + threadIdx.x;
    const int m1 = m0 + 256;
    const float q0x = up_points[3 * m0];
    const float q0y = up_points[3 * m0 + 1];
    const float q0z = up_points[3 * m0 + 2];
    const float q1x = up_points[3 * m1];
    const float q1y = up_points[3 * m1 + 1];
    const float q1z = up_points[3 * m1 + 2];

    float a_gd0 = FLT_MAX, a_gd1 = FLT_MAX, a_gd2 = FLT_MAX;
    int   a_gi0 = 0, a_gi1 = 0, a_gi2 = 0;
    float b_gd0 = FLT_MAX, b_gd1 = FLT_MAX, b_gd2 = FLT_MAX;
    int   b_gi0 = 0, b_gi1 = 0, b_gi2 = 0;

    for (int gi = 0; gi < CHUNK / G; ++gi) {
        float4 x0 = *(const float4*)&sx[PG * gi], x1 = *(const float4*)&sx[PG * gi + 4];
        float4 y0 = *(const float4*)&sy[PG * gi], y1 = *(const float4*)&sy[PG * gi + 4];
        float4 z0 = *(const float4*)&sz[PG * gi], z1 = *(const float4*)&sz[PG * gi + 4];
        float px[G] = {x0.x, x0.y, x0.z, x0.w, x1.x, x1.y, x1.z, x1.w};
        float py[G] = {y0.x, y0.y, y0.z, y0.w, y1.x, y1.y, y1.z, y1.w};
        float pz[G] = {z0.x, z0.y, z0.z, z0.w, z1.x, z1.y, z1.z, z1.w};
        float s0[G], s1[G];
        #pragma unroll
        for (int j = 0; j < G; ++j) {
            float dx0 = q0x - px[j], dy0 = q0y - py[j], dz0 = q0z - pz[j];
            s0[j] = fmaf(dz0, dz0, fmaf(dy0, dy0, dx0 * dx0));
            float dx1 = q1x - px[j], dy1 = q1y - py[j], dz1 = q1z - pz[j];
            s1[j] = fmaf(dz1, dz1, fmaf(dy1, dy1, dx1 * dx1));
        }
        float gm0 = fminf(fminf(fminf(s0[0], s0[1]), fminf(s0[2], s0[3])),
                          fminf(fminf(s0[4], s0[5]), fminf(s0[6], s0[7])));
        float gm1 = fminf(fminf(fminf(s1[0], s1[1]), fminf(s1[2], s1[3])),
                          fminf(fminf(s1[4], s1[5]), fminf(s1[6], s1[7])));
        top3_bl(gm0, gi, a_gd0, a_gd1, a_gd2, a_gi0, a_gi1, a_gi2);
        top3_bl(gm1, gi, b_gd0, b_gd1, b_gd2, b_gi0, b_gi1, b_gi2);
    }

    // exact refine over the 3 winning groups (24 points per query)
    #pragma unroll
    for (int qq = 0; qq < Q; ++qq) {
        const float qx = qq ? q1x : q0x;
        const float qy = qq ? q1y : q0y;
        const float qz = qq ? q1z : q0z;
        int bases[3];
        if (qq == 0) { bases[0] = a_gi0; bases[1] = a_gi1; bases[2] = a_gi2; }
        else         { bases[0] = b_gi0; bases[1] = b_gi1; bases[2] = b_gi2; }
        float D0 = FLT_MAX, D1 = FLT_MAX, D2 = FLT_MAX;
        int I0 = 0, I1 = 0, I2 = 0;
        #pragma unroll
        for (int t = 0; t < 3; ++t) {
            const int gb = bases[t];
            float4 x0 = *(const float4*)&sx[PG * gb], x1 = *(const float4*)&sx[PG * gb + 4];
            float4 y0 = *(const float4*)&sy[PG * gb], y1 = *(const float4*)&sy[PG * gb + 4];
            float4 z0 = *(const float4*)&sz[PG * gb], z1 = *(const float4*)&sz[PG * gb + 4];
            float px[G] = {x0.x, x0.y, x0.z, x0.w, x1.x, x1.y, x1.z, x1.w};
            float py[G] = {y0.x, y0.y, y0.z, y0.w, y1.x, y1.y, y1.z, y1.w};
            float pz[G] = {z0.x, z0.y, z0.z, z0.w, z1.x, z1.y, z1.z, z1.w};
            #pragma unroll
            for (int j = 0; j < G; ++j) {
                float dx = qx - px[j], dy = qy - py[j], dz = qz - pz[j];
                float s = fmaf(dz, dz, fmaf(dy, dy, dx * dx));
                top3_bl(s, base + gb * G + j, D0, D1, D2, I0, I1, I2);
            }
        }
        const int m = qq ? m1 : m0;
        const int o = (blockIdx.y * M_UP + m) * 3;
        part[o]     = make_float2(D0, __int_as_float(I0));
        part[o + 1] = make_float2(D1, __int_as_float(I1));
        part[o + 2] = make_float2(D2, __int_as_float(I2));
    }
}

// ---------------------------------------------------------------------------
// K3: fused up-projection + top-3 merge + interpolation + bias + add.
// Register-blocked GEMM (32-row tile, 1024 blocks) + per-row merge epilogue.
// Merge insert order (s,j) ascending preserved -> same tie-break semantics.
// ---------------------------------------------------------------------------
__global__ __launch_bounds__(256) void up_fused(
        const float* __restrict__ A, const float* __restrict__ WT,
        const float* __restrict__ bias, const float* __restrict__ down_f,
        const float2* __restrict__ part,
        float* __restrict__ out) {
    __shared__ __align__(16) float sA[32 * 36];
    __shared__ __align__(16) float sW[32 * OUTC];
    float4 acc[2][2] = {};
    gemm_tile32<UPC>(A, WT, sA, sW, blockIdx.x * 32, threadIdx.x, acc);

    const int rl = threadIdx.x & 15;
    const int cg = (threadIdx.x >> 4) * 2;       // col float4 index
    const float4 b0 = ((const float4*)bias)[cg];
    const float4 b1 = ((const float4*)bias)[cg + 1];
    const float4* df4 = (const float4*)down_f;
    #pragma unroll
    for (int i = 0; i < 2; ++i) {
        const int m = blockIdx.x * 32 + rl + 16 * i;
        float D0 = FLT_MAX, D1 = FLT_MAX, D2 = FLT_MAX;
        int I0 = 0, I1 = 0, I2 = 0;
        #pragma unroll
        for (int s = 0; s < NCHUNK; ++s) {
            const float2* p = part + (s * M_UP + m) * 3;
            #pragma unroll
            for (int j = 0; j < 3; ++j) {
                float2 v = p[j];
                top3_bl(v.x, __float_as_int(v.y), D0, D1, D2, I0, I1, I2);
            }
        }
        float r0 = 1.f / (D0 + 1e-8f);
        float r1 = 1.f / (D1 + 1e-8f);
        float r2 = 1.f / (D2 + 1e-8f);
        float rs = (r0 + r1) + r2;
        float w0 = r0 / rs, w1 = r1 / rs, w2 = r2 / rs;
        float4 f00 = df4[I0 * 32 + cg],     f01 = df4[I0 * 32 + cg + 1];
        float4 f10 = df4[I1 * 32 + cg],     f11 = df4[I1 * 32 + cg + 1];
        float4 f20 = df4[I2 * 32 + cg],     f21 = df4[I2 * 32 + cg + 1];
        float4 v0 = acc[i][0], v1 = acc[i][1];
        float4 res0, res1;
        res0.x = v0.x + b0.x + fmaf(w0, f00.x, fmaf(w1, f10.x, w2 * f20.x));
        res0.y = v0.y + b0.y + fmaf(w0, f00.y, fmaf(w1, f10.y, w2 * f20.y));
        res0.z = v0.z + b0.z + fmaf(w0, f00.z, fmaf(w1, f10.z, w2 * f20.z));
        res0.w = v0.w + b0.w + fmaf(w0, f00.w, fmaf(w1, f10.w, w2 * f20.w));
        res1.x = v1.x + b1.x + fmaf(w0, f01.x, fmaf(w1, f11.x, w2 * f21.x));
        res1.y = v1.y + b1.y + fmaf(w0, f01.y, fmaf(w1, f11.y, w2 * f21.y));
        res1.z = v1.z + b1.z + fmaf(w0, f01.z, fmaf(w1, f11.z, w2 * f21.z));
        res1.w = v1.w + b1.w + fmaf(w0, f01.w, fmaf(w1, f11.w, w2 * f21.w));
        ((float4*)out)[m * 32 + cg] = res0;
        ((float4*)out)[m * 32 + cg + 1] = res1;
    }
}

extern "C" void kernel_launch(void* const* d_in, const int* in_sizes, int n_in,
                              void* d_out, int out_size, void* d_ws, size_t ws_size,
                              hipStream_t stream) {
    const float* up_points     = (const float*)d_in[0];
    const float* up_features   = (const float*)d_in[1];
    const float* down_points   = (const float*)d_in[2];
    const float* down_features = (const float*)d_in[3];
    const float* W_up          = (const float*)d_in[4];
    const float* b_up          = (const float*)d_in[5];
    const float* W_down        = (const float*)d_in[6];
    const float* b_down        = (const float*)d_in[7];
    float* out = (float*)d_out;

    float* wt_down = (float*)d_ws;                         // 256*128
    float* wt_up   = wt_down + DOWNC * OUTC;               // 128*128
    float* down_f  = wt_up + UPC * OUTC;                   // 8192*128
    float2* part   = (float2*)(down_f + N_DOWN * OUTC);    // NCHUNK*32768*3 float2
    // total ~10.7 MB (proven R0/R7 footprint)

    transpose_w<<<(DOWNC * OUTC + UPC * OUTC) / 256, 256, 0, stream>>>(
        W_up, W_down, wt_up, wt_down);
    down_proj<<<N_DOWN / 32, 256, 0, stream>>>(
        down_features, wt_down, b_down, down_f);
    knn_partial<<<dim3(M_UP / (256 * Q), NCHUNK), 256, 0, stream>>>(
        up_points, down_points, part);
    up_fused<<<M_UP / 32, 256, 0, stream>>>(
        up_features, wt_up, b_up, down_f, part, out);
}